// Round 6
// baseline (343.958 us; speedup 1.0000x reference)
//
#include <hip/hip_runtime.h>
#include <stdint.h>

typedef unsigned short u16;
typedef __bf16 bf16_t;
typedef bf16_t bf16x8 __attribute__((ext_vector_type(8)));
typedef float f32x4 __attribute__((ext_vector_type(4)));
typedef u16 u16x4 __attribute__((ext_vector_type(4)));
typedef u16 u16x8 __attribute__((ext_vector_type(8)));

#define AS1 __attribute__((address_space(1)))
#define AS3 __attribute__((address_space(3)))

__device__ __forceinline__ u16 f2bf(float f) {
  union { float f; uint32_t u; } x; x.f = f;
  uint32_t u = x.u;
  return (u16)((u + 0x7fffu + ((u >> 16) & 1u)) >> 16);  // RNE
}

__device__ __forceinline__ float bf2f(u16 b) {
  union { uint32_t u; float f; } x; x.u = ((uint32_t)b) << 16;
  return x.f;
}

__device__ __forceinline__ void gload_lds16(const void* g, void* lds) {
  __builtin_amdgcn_global_load_lds((const AS1 uint32_t*)g, (AS3 uint32_t*)lds, 16, 0, 0);
}

// ---------------------------------------------------------------------------
// fp32 -> bf16 elementwise convert
// ---------------------------------------------------------------------------
__global__ __launch_bounds__(256) void cvt_bf16(const float* __restrict__ in,
                                                u16* __restrict__ out, int n4) {
  int i = blockIdx.x * 256 + threadIdx.x;
  if (i >= n4) return;
  float4 v = ((const float4*)in)[i];
  u16x4 o = {f2bf(v.x), f2bf(v.y), f2bf(v.z), f2bf(v.w)};
  *(u16x4*)(out + (size_t)i * 4) = o;
}

// ---------------------------------------------------------------------------
// 256x256 bf16 MFMA GEMM (C = A * B^T), reg-double-buffered, B DIRECT-GLOBAL.
// Rounds 0/1/3/4/5 post-mortem: five different sync structures all land
// 65-75us => bottleneck is a resource, not the schedule. LDS moved 256KB
// per tile per CU (A+B staged 64KB + frag reads 192KB) ~ 2800cyc of port
// time; MFMA 2060cyc; measured 4875 ~ SUM. Fix: B (L2-resident panel in
// all 4 GEMMs of this net: Wib 6MB / k-part / vT 4MB / Wob 2MB) is loaded
// global->VGPR directly (4x16B per quadrant, one 128B line per row, no
// XOR -- no banks in L2), never touching LDS. LDS traffic 256->160KB/tile.
// Same global bytes as staging read before => FETCH unchanged. Mid-tile
// vmcnt(0) now drains only the 4 A-staging ops (B loads auto-drained by
// compiler dependence waits, queue order oldest-first works in our favor).
// Loop body otherwise = round-3 winner. LDS 64KiB (As only).
// A: [M][K] stride lda, B: [N][K] stride ldb, C: [M][N] stride ldc.
// z-batch via sAz/sBz/sCz. M=gridDim.y*256, N=gridDim.x*256, K%64==0, nt>=2.
// ---------------------------------------------------------------------------
#define BARRIER() do { asm volatile("" ::: "memory"); \
                       __builtin_amdgcn_s_barrier();  \
                       asm volatile("" ::: "memory"); } while (0)

#define MQS(MQi, NQi, ASET, BSET)                                              \
  do {                                                                         \
    __builtin_amdgcn_s_setprio(1);                                             \
    _Pragma("unroll") for (int j_ = 0; j_ < 4; ++j_) {                         \
      _Pragma("unroll") for (int i_ = 0; i_ < 2; ++i_) {                       \
        acc[(MQi) * 4 + j_][(NQi) * 2 + i_] =                                  \
            __builtin_amdgcn_mfma_f32_16x16x32_bf16(                           \
                ASET[j_][0], BSET[i_][0],                                      \
                acc[(MQi) * 4 + j_][(NQi) * 2 + i_], 0, 0, 0);                 \
        acc[(MQi) * 4 + j_][(NQi) * 2 + i_] =                                  \
            __builtin_amdgcn_mfma_f32_16x16x32_bf16(                           \
                ASET[j_][1], BSET[i_][1],                                      \
                acc[(MQi) * 4 + j_][(NQi) * 2 + i_], 0, 0, 0);                 \
      }                                                                        \
    }                                                                          \
    __builtin_amdgcn_s_setprio(0);                                             \
  } while (0)

template <bool BF16OUT>
__global__ __launch_bounds__(512, 2)
void gemm256(const u16* __restrict__ A, const u16* __restrict__ B,
             void* __restrict__ Cv,
             int lda, int ldb, int ldc,
             long long sAz, long long sBz, long long sCz,
             int K, float alpha) {
  __shared__ u16 As[2][256 * 64];   // 64 KiB total (B is never staged)
  const int tid  = threadIdx.x;
  const int lane = tid & 63;
  const int wid  = tid >> 6;        // 0..7
  const int wr   = wid >> 2;        // 0..1
  const int wc   = wid & 3;         // 0..3
  const long long z = blockIdx.z;
  const u16* Ab = A + z * sAz;
  const u16* Bb = B + z * sBz;
  const int rowBase = blockIdx.y * 256;
  const int colBase = blockIdx.x * 256;
  const int nt = K >> 6;

  // A staging: thread t covers LDS linear chunk (row = h*128 + i*64 + t/8,
  // chunkpos = t&7); source chunk pre-swizzled with the reader's XOR
  // (rule 21: both-sides involution). Same 128B row segment -> coalesced.
  const int sRow   = tid >> 3;                    // 0..63
  const int sChunk = (tid & 7) ^ (sRow & 7);
  const size_t ldaS = (size_t)lda, ldbS = (size_t)ldb;
  const u16* aS = Ab + (size_t)(rowBase + sRow) * ldaS + sChunk * 8;

  const int fr = lane & 15;   // fragment row within 16
  const int kx = lane >> 4;   // k-group 0..3
  const int rx = lane & 7;    // swizzle key (== frag row & 7)

  f32x4 acc[8][4];
  const f32x4 zf = {0.f, 0.f, 0.f, 0.f};
#pragma unroll
  for (int m = 0; m < 8; ++m)
#pragma unroll
    for (int n = 0; n < 4; ++n) acc[m][n] = zf;

  // double-buffered operand fragment sets (static indexing only, rule #20)
  bf16x8 Ara[4][2], Arb[4][2], Bra[2][2], Brb[2][2];

  // A half-tile stage = 2 gload_lds per thread (full A tile = 2 calls).
  auto stageA = [&](int buf, int h, int kt) {
    const u16* s = aS + (size_t)(h * 128) * ldaS + kt;
    char* d = ((char*)&As[buf][0]) + h * 16384 + tid * 16;
    gload_lds16(s, d);
    gload_lds16(s + 64 * ldaS, d + 8192);
  };
  auto ldsA = [&](int buf, int mq, bf16x8 (&dst)[4][2]) {
#pragma unroll
    for (int j = 0; j < 4; ++j) {
      const int row = mq * 128 + wr * 64 + j * 16 + fr;
#pragma unroll
      for (int k = 0; k < 2; ++k) {
        const int ch = ((k * 4 + kx) ^ rx) * 8;
        dst[j][k] = *(const bf16x8*)&As[buf][row * 64 + ch];
      }
    }
  };
  // B fragments straight from global (L2/L1-resident panel). Per call:
  // 4 x 16B loads/lane; per row the kx*k chunks tile one 128B line exactly.
  auto gloadB = [&](bf16x8 (&dst)[2][2], int nq, int kt) {
#pragma unroll
    for (int i = 0; i < 2; ++i) {
      const u16* src =
          Bb + (size_t)(colBase + nq * 128 + i * 64 + wc * 16 + fr) * ldbS + kt;
#pragma unroll
      for (int k = 0; k < 2; ++k) {
        dst[i][k] = *(const bf16x8*)(src + (k * 4 + kx) * 8);
      }
    }
  };

  // prologue: A(0) -> As[0]; B0(0) -> regs.
  stageA(0, 0, 0);
  stageA(0, 1, 0);
  gloadB(Bra, 0, 0);
  asm volatile("s_waitcnt vmcnt(0)" ::: "memory");
  __builtin_amdgcn_sched_barrier(0);
  BARRIER();
  ldsA(0, 0, Ara);              // A0(0)

  for (int t = 0; t < nt; ++t) {
    const int c = t & 1;
    const int kt0 = t << 6;
    const int kt1 = (t + 1) << 6;
    const bool s1 = (t + 1 < nt);
    // pre-MFMA issue block: B1(t) global, A1(t) ds_reads, A(t+1) staging.
    gloadB(Brb, 1, kt0);        // B1(t); cover = MQ(0,0)
    ldsA(c, 1, Arb);            // A1(t), 8 reads; consumer MQ(1,0)
    if (s1) {
      stageA(1 - c, 0, kt1);    // 4 vmem: full A tile t+1 -> As[1-c]
      stageA(1 - c, 1, kt1);
    }
    __builtin_amdgcn_sched_barrier(0);  // pin: loads issue before MFMA
    MQS(0, 0, Ara, Bra);
    MQS(0, 1, Ara, Brb);
    if (s1) {
      // A1(t) reads served before next iter's staging overwrites As[c];
      // vmcnt(0) drains only the 4 A-staging ops (Brb already consumed).
      asm volatile("s_waitcnt lgkmcnt(0)" ::: "memory");
      asm volatile("s_waitcnt vmcnt(0)" ::: "memory");
      BARRIER();
      ldsA(1 - c, 0, Ara);      // A0(t+1), 8 reads; drains under MQ(1,0)
      __builtin_amdgcn_sched_barrier(0);
    }
    MQS(1, 0, Arb, Bra);        // last use of Bra=B0(t)
    if (s1) gloadB(Bra, 0, kt1);// B0(t+1); cover = MQ(1,1)+loop
    MQS(1, 1, Arb, Brb);
    // invariant restored: Ara=A0(t+1), Bra=B0(t+1)
  }

  // epilogue: C/D layout col=lane&15, row=(lane>>4)*4+reg [m89-verified]
  const int r0 = (lane >> 4) * 4;
#pragma unroll
  for (int m = 0; m < 8; ++m) {
    const int grow = rowBase + (m >> 2) * 128 + wr * 64 + (m & 3) * 16 + r0;
#pragma unroll
    for (int jj = 0; jj < 4; ++jj) {
      const size_t rOff = (size_t)(grow + jj) * (size_t)ldc;
      if constexpr (BF16OUT) {
        u16* C = (u16*)Cv + z * sCz;
#pragma unroll
        for (int n = 0; n < 4; ++n) {
          const int gcol = colBase + (n >> 1) * 128 + (n & 1) * 64 + wc * 16 + fr;
          C[rOff + gcol] = f2bf(acc[m][n][jj] * alpha);
        }
      } else {
        float* C = (float*)Cv + z * sCz;
#pragma unroll
        for (int n = 0; n < 4; ++n) {
          const int gcol = colBase + (n >> 1) * 128 + (n & 1) * 64 + wc * 16 + fr;
          C[rOff + gcol] = acc[m][n][jj] * alpha;
        }
      }
    }
  }
}

// ---------------------------------------------------------------------------
// v transpose: qkv[(t*4+b)*3072 + 2048 + e] -> vT[b][e][t]  (bf16)
// ---------------------------------------------------------------------------
__global__ __launch_bounds__(256)
void transpose_v(const u16* __restrict__ qkv, u16* __restrict__ vT) {
  __shared__ u16 tile[64][72];
  const int b  = blockIdx.z;
  const int t0 = blockIdx.x * 64;
  const int e0 = blockIdx.y * 64;
  const int tid = threadIdx.x;
  const int r  = tid >> 3;
  const int c8 = (tid & 7) * 8;
#pragma unroll
  for (int p = 0; p < 2; ++p) {
    const int t = t0 + p * 32 + r;
    const u16* src = qkv + (size_t)(t * 4 + b) * 3072 + 2048 + e0 + c8;
    *(u16x8*)&tile[p * 32 + r][c8] = *(const u16x8*)src;
  }
  __syncthreads();
#pragma unroll
  for (int p = 0; p < 2; ++p) {
    const int e = p * 32 + r;
    u16x8 v;
#pragma unroll
    for (int j = 0; j < 8; ++j) v[j] = tile[c8 + j][e];
    *(u16x8*)(vT + (size_t)b * 2097152 + (size_t)(e0 + e) * 2048 + t0 + c8) = v;
  }
}

// ---------------------------------------------------------------------------
// Row softmax over 2048 cols: reads bf16 scores (already scaled by 1/32),
// writes fp32 weights (required output) + bf16 probs IN PLACE over scores.
// ---------------------------------------------------------------------------
__global__ __launch_bounds__(256)
void softmax_rows(u16* __restrict__ sbf, float* __restrict__ wfp) {
  const size_t row = blockIdx.x;
  const int tid = threadIdx.x;
  u16* pb = sbf + row * 2048;
  u16x8 xb = *(const u16x8*)(pb + tid * 8);
  float x[8];
#pragma unroll
  for (int j = 0; j < 8; ++j) x[j] = bf2f(xb[j]);
  float m = x[0];
#pragma unroll
  for (int j = 1; j < 8; ++j) m = fmaxf(m, x[j]);
#pragma unroll
  for (int o = 32; o; o >>= 1) m = fmaxf(m, __shfl_xor(m, o, 64));
  __shared__ float red[8];
  if ((tid & 63) == 0) red[tid >> 6] = m;
  __syncthreads();
  m = fmaxf(fmaxf(red[0], red[1]), fmaxf(red[2], red[3]));
  float e[8];
  float s = 0.f;
#pragma unroll
  for (int j = 0; j < 8; ++j) { e[j] = expf(x[j] - m); s += e[j]; }
#pragma unroll
  for (int o = 32; o; o >>= 1) s += __shfl_xor(s, o, 64);
  if ((tid & 63) == 0) red[4 + (tid >> 6)] = s;
  __syncthreads();
  s = (red[4] + red[5]) + (red[6] + red[7]);
  const float inv = 1.0f / s;
  float w[8];
#pragma unroll
  for (int j = 0; j < 8; ++j) w[j] = e[j] * inv;
  float* pf = wfp + row * 2048;
  float4 o0 = {w[0], w[1], w[2], w[3]};
  float4 o1 = {w[4], w[5], w[6], w[7]};
  ((float4*)pf)[tid * 2] = o0;
  ((float4*)pf)[tid * 2 + 1] = o1;
  u16x8 ub;
#pragma unroll
  for (int j = 0; j < 8; ++j) ub[j] = f2bf(w[j]);
  *(u16x8*)(pb + tid * 8) = ub;
}

// ---------------------------------------------------------------------------
// S=2048, B=4, E=1024. inputs: Q, K(ignored), V(ignored), W_in, W_out (fp32)
// outputs: out [2048,4,1024] fp32 | weights [4,2048,2048] fp32
// ---------------------------------------------------------------------------
extern "C" void kernel_launch(void* const* d_in, const int* in_sizes, int n_in,
                              void* d_out, int out_size, void* d_ws, size_t ws_size,
                              hipStream_t stream) {
  const float* Q  = (const float*)d_in[0];
  const float* Wi = (const float*)d_in[3];
  const float* Wo = (const float*)d_in[4];
  float* out0    = (float*)d_out;
  float* weights = out0 + (size_t)2048 * 4 * 1024;  // 8388608

  char* ws = (char*)d_ws;
  u16* Qb   = (u16*)(ws);                          // 16 MiB [8192][1024]
  u16* Wib  = (u16*)(ws + ((size_t)16 << 20));     //  6 MiB [3072][1024]
  u16* Wob  = (u16*)(ws + ((size_t)22 << 20));     //  2 MiB [1024][1024]
  u16* qkvb = (u16*)(ws + ((size_t)24 << 20));     // 48 MiB [8192][3072]
  u16* vT   = (u16*)(ws + ((size_t)72 << 20));     // 16 MiB [4][1024][2048]
  u16* wbf  = (u16*)(ws + ((size_t)88 << 20));     // 32 MiB [4][2048][2048]
  u16* attb = Qb;  // alias: Qb dead after gemm1. [t][b][e] = [8192][1024]

  // 1) converts
  cvt_bf16<<<dim3(8192), dim3(256), 0, stream>>>(Q,  Qb,  2097152);
  cvt_bf16<<<dim3(3072), dim3(256), 0, stream>>>(Wi, Wib, 786432);
  cvt_bf16<<<dim3(1024), dim3(256), 0, stream>>>(Wo, Wob, 262144);

  // 2) qkv = Q * W_in^T : [8192,1024] x [3072,1024]^T -> bf16 [8192,3072]
  gemm256<true><<<dim3(12, 32, 1), dim3(512), 0, stream>>>(
      Qb, Wib, (void*)qkvb, 1024, 1024, 3072, 0, 0, 0, 1024, 1.0f);

  // 3) vT[b][e][t] from qkv v-part
  transpose_v<<<dim3(32, 16, 4), dim3(256), 0, stream>>>(qkvb, vT);

  // 4) scores[b] = (q/32) k^T -> bf16 directly into wbf (no fp32 round-trip)
  gemm256<true><<<dim3(8, 8, 4), dim3(512), 0, stream>>>(
      qkvb, qkvb + 1024, (void*)wbf, 12288, 12288, 2048,
      3072LL, 3072LL, 4194304LL, 1024, 0.03125f);

  // 5) softmax: bf16 scores -> fp32 weights (d_out) + bf16 probs in place
  softmax_rows<<<dim3(8192), dim3(256), 0, stream>>>(wbf, weights);

  // 6) att[t][b][e] = probs[b] * v[b]  (B = vT)
  gemm256<true><<<dim3(4, 8, 4), dim3(512), 0, stream>>>(
      wbf, vT, (void*)attb, 2048, 2048, 4096,
      4194304LL, 2097152LL, 1024LL, 2048, 1.0f);

  // 7) out = att * W_out^T -> fp32 d_out
  gemm256<false><<<dim3(4, 32, 1), dim3(512), 0, stream>>>(
      attb, Wob, (void*)out0, 1024, 1024, 1024, 0, 0, 0, 1024, 1.0f);
}

// Round 7
// 220.976 us; speedup vs baseline: 1.5565x; 1.5565x over previous
//
#include <hip/hip_runtime.h>
#include <stdint.h>

typedef unsigned short u16;
typedef __bf16 bf16_t;
typedef bf16_t bf16x8 __attribute__((ext_vector_type(8)));
typedef float f32x4 __attribute__((ext_vector_type(4)));
typedef u16 u16x4 __attribute__((ext_vector_type(4)));
typedef u16 u16x8 __attribute__((ext_vector_type(8)));

#define AS1 __attribute__((address_space(1)))
#define AS3 __attribute__((address_space(3)))

__device__ __forceinline__ u16 f2bf(float f) {
  union { float f; uint32_t u; } x; x.f = f;
  uint32_t u = x.u;
  return (u16)((u + 0x7fffu + ((u >> 16) & 1u)) >> 16);  // RNE
}

__device__ __forceinline__ float bf2f(u16 b) {
  union { uint32_t u; float f; } x; x.u = ((uint32_t)b) << 16;
  return x.f;
}

__device__ __forceinline__ void gload_lds16(const void* g, void* lds) {
  __builtin_amdgcn_global_load_lds((const AS1 uint32_t*)g, (AS3 uint32_t*)lds, 16, 0, 0);
}

// ---------------------------------------------------------------------------
// fp32 -> bf16 elementwise convert
// ---------------------------------------------------------------------------
__global__ __launch_bounds__(256) void cvt_bf16(const float* __restrict__ in,
                                                u16* __restrict__ out, int n4) {
  int i = blockIdx.x * 256 + threadIdx.x;
  if (i >= n4) return;
  float4 v = ((const float4*)in)[i];
  u16x4 o = {f2bf(v.x), f2bf(v.y), f2bf(v.z), f2bf(v.w)};
  *(u16x4*)(out + (size_t)i * 4) = o;
}

// ---------------------------------------------------------------------------
// Shared GEMM machinery. Session record (r0-r6): per 256x256x64 tile, time
// ~4875cyc == LDS-port (~2800) + MFMA (~2060), SUM behavior, invariant
// across 5 schedule variants; B-direct-global regressed (L2 latency not
// coverable). Per-block MfmaUtil ~42%; dispatch-level packing is the other
// loss: att/out grids were 128 blocks on a 256-CU machine (1 block/CU,
// register-pinned). This round: gemm256 = round-3 winner (unchanged);
// gemm128 = 128x256-tile variant for att/out so their grids hit 256 blocks.
// ---------------------------------------------------------------------------
#define BARRIER() do { asm volatile("" ::: "memory"); \
                       __builtin_amdgcn_s_barrier();  \
                       asm volatile("" ::: "memory"); } while (0)

#define MQS(MQi, NQi, ASET, BSET)                                              \
  do {                                                                         \
    __builtin_amdgcn_s_setprio(1);                                             \
    _Pragma("unroll") for (int j_ = 0; j_ < 4; ++j_) {                         \
      _Pragma("unroll") for (int i_ = 0; i_ < 2; ++i_) {                       \
        acc[(MQi) * 4 + j_][(NQi) * 2 + i_] =                                  \
            __builtin_amdgcn_mfma_f32_16x16x32_bf16(                           \
                ASET[j_][0], BSET[i_][0],                                      \
                acc[(MQi) * 4 + j_][(NQi) * 2 + i_], 0, 0, 0);                 \
        acc[(MQi) * 4 + j_][(NQi) * 2 + i_] =                                  \
            __builtin_amdgcn_mfma_f32_16x16x32_bf16(                           \
                ASET[j_][1], BSET[i_][1],                                      \
                acc[(MQi) * 4 + j_][(NQi) * 2 + i_], 0, 0, 0);                 \
      }                                                                        \
    }                                                                          \
    __builtin_amdgcn_s_setprio(0);                                             \
  } while (0)

// ---------------------------------------------------------------------------
// gemm256: 256x256 tile, 8 waves 2Mx4N, reg-dbuf (round-3 winner, verified
// 65us/qkv). A: [M][K] lda, B: [N][K] ldb, C: [M][N] ldc, z via sAz/sBz/sCz.
// M=gridDim.y*256, N=gridDim.x*256, K%64==0, nt>=2.
// ---------------------------------------------------------------------------
template <bool BF16OUT>
__global__ __launch_bounds__(512, 2)
void gemm256(const u16* __restrict__ A, const u16* __restrict__ B,
             void* __restrict__ Cv,
             int lda, int ldb, int ldc,
             long long sAz, long long sBz, long long sCz,
             int K, float alpha) {
  __shared__ u16 As[2][256 * 64];   // 64 KiB
  __shared__ u16 Bs[2][256 * 64];   // 64 KiB
  const int tid  = threadIdx.x;
  const int lane = tid & 63;
  const int wid  = tid >> 6;        // 0..7
  const int wr   = wid >> 2;        // 0..1
  const int wc   = wid & 3;         // 0..3
  const long long z = blockIdx.z;
  const u16* Ab = A + z * sAz;
  const u16* Bb = B + z * sBz;
  const int rowBase = blockIdx.y * 256;
  const int colBase = blockIdx.x * 256;
  const int nt = K >> 6;

  const int sRow   = tid >> 3;                    // 0..63
  const int sChunk = (tid & 7) ^ (sRow & 7);      // rule-21 involution
  const size_t ldaS = (size_t)lda, ldbS = (size_t)ldb;
  const u16* aS = Ab + (size_t)(rowBase + sRow) * ldaS + sChunk * 8;
  const u16* bS = Bb + (size_t)(colBase + sRow) * ldbS + sChunk * 8;

  const int fr = lane & 15;
  const int kx = lane >> 4;
  const int rx = lane & 7;

  f32x4 acc[8][4];
  const f32x4 zf = {0.f, 0.f, 0.f, 0.f};
#pragma unroll
  for (int m = 0; m < 8; ++m)
#pragma unroll
    for (int n = 0; n < 4; ++n) acc[m][n] = zf;

  bf16x8 Ara[4][2], Arb[4][2], Bra[2][2], Brb[2][2];

  auto stageA = [&](int buf, int h, int kt) {
    const u16* s = aS + (size_t)(h * 128) * ldaS + kt;
    char* d = ((char*)&As[buf][0]) + h * 16384 + tid * 16;
    gload_lds16(s, d);
    gload_lds16(s + 64 * ldaS, d + 8192);
  };
  auto stageB = [&](int buf, int h, int kt) {
    const u16* s = bS + (size_t)(h * 128) * ldbS + kt;
    char* d = ((char*)&Bs[buf][0]) + h * 16384 + tid * 16;
    gload_lds16(s, d);
    gload_lds16(s + 64 * ldbS, d + 8192);
  };
  auto ldsA = [&](int buf, int mq, bf16x8 (&dst)[4][2]) {
#pragma unroll
    for (int j = 0; j < 4; ++j) {
      const int row = mq * 128 + wr * 64 + j * 16 + fr;
#pragma unroll
      for (int k = 0; k < 2; ++k) {
        const int ch = ((k * 4 + kx) ^ rx) * 8;
        dst[j][k] = *(const bf16x8*)&As[buf][row * 64 + ch];
      }
    }
  };
  auto ldsB = [&](int buf, int nq, bf16x8 (&dst)[2][2]) {
#pragma unroll
    for (int i = 0; i < 2; ++i) {
      const int row = nq * 128 + i * 64 + wc * 16 + fr;
#pragma unroll
      for (int k = 0; k < 2; ++k) {
        const int ch = ((k * 4 + kx) ^ rx) * 8;
        dst[i][k] = *(const bf16x8*)&Bs[buf][row * 64 + ch];
      }
    }
  };

  stageA(0, 0, 0);
  stageA(0, 1, 0);
  stageB(0, 0, 0);
  stageB(0, 1, 0);
  asm volatile("s_waitcnt vmcnt(0)" ::: "memory");
  BARRIER();
  ldsA(0, 0, Ara);              // A0(0)
  ldsB(0, 0, Bra);              // B0(0)

  for (int t = 0; t < nt; ++t) {
    const int c = t & 1;
    const int kt1 = (t + 1) << 6;
    const bool s1 = (t + 1 < nt);
    ldsB(c, 1, Brb);            // B1(t)
    ldsA(c, 1, Arb);            // A1(t)
    if (s1) {
      stageA(1 - c, 0, kt1);
      stageA(1 - c, 1, kt1);
      stageB(1 - c, 0, kt1);
      stageB(1 - c, 1, kt1);
    }
    MQS(0, 0, Ara, Bra);
    MQS(0, 1, Ara, Brb);
    if (s1) {
      asm volatile("s_waitcnt lgkmcnt(0)" ::: "memory");
      asm volatile("s_waitcnt vmcnt(0)" ::: "memory");
      BARRIER();
      ldsA(1 - c, 0, Ara);      // A0(t+1)
      __builtin_amdgcn_sched_barrier(0);
    }
    MQS(1, 0, Arb, Bra);
    if (s1) ldsB(1 - c, 0, Bra);// B0(t+1)
    MQS(1, 1, Arb, Brb);
  }

  const int r0 = (lane >> 4) * 4;
#pragma unroll
  for (int m = 0; m < 8; ++m) {
    const int grow = rowBase + (m >> 2) * 128 + wr * 64 + (m & 3) * 16 + r0;
#pragma unroll
    for (int jj = 0; jj < 4; ++jj) {
      const size_t rOff = (size_t)(grow + jj) * (size_t)ldc;
      if constexpr (BF16OUT) {
        u16* C = (u16*)Cv + z * sCz;
#pragma unroll
        for (int n = 0; n < 4; ++n) {
          const int gcol = colBase + (n >> 1) * 128 + (n & 1) * 64 + wc * 16 + fr;
          C[rOff + gcol] = f2bf(acc[m][n][jj] * alpha);
        }
      } else {
        float* C = (float*)Cv + z * sCz;
#pragma unroll
        for (int n = 0; n < 4; ++n) {
          const int gcol = colBase + (n >> 1) * 128 + (n & 1) * 64 + wc * 16 + fr;
          C[rOff + gcol] = acc[m][n][jj] * alpha;
        }
      }
    }
  }
}

// ---------------------------------------------------------------------------
// gemm128: 128x256 tile (packing variant for grids that would be <256
// blocks at 256^2). 8 waves 2Mx4N, wave owns 64x64, acc[4][4]. A dbuf reg
// sets alternate per tile via compile-time unroll-of-2 (rule #20: static
// indexing); B reg sets have fixed roles (B0 overwritten post-consume each
// tile). LDS 96KiB: As[2][128x64] 32K + Bs[2][256x64] 64K. Requires
// nt = K/64 EVEN and >= 2. M=gridDim.y*128, N=gridDim.x*256.
// ---------------------------------------------------------------------------
template <bool BF16OUT>
__global__ __launch_bounds__(512, 2)
void gemm128(const u16* __restrict__ A, const u16* __restrict__ B,
             void* __restrict__ Cv,
             int lda, int ldb, int ldc,
             long long sAz, long long sBz, long long sCz,
             int K, float alpha) {
  __shared__ u16 As[2][128 * 64];   // 32 KiB
  __shared__ u16 Bs[2][256 * 64];   // 64 KiB
  const int tid  = threadIdx.x;
  const int lane = tid & 63;
  const int wid  = tid >> 6;        // 0..7
  const int wr   = wid >> 2;        // 0..1
  const int wc   = wid & 3;         // 0..3
  const long long z = blockIdx.z;
  const u16* Ab = A + z * sAz;
  const u16* Bb = B + z * sBz;
  const int rowBase = blockIdx.y * 128;
  const int colBase = blockIdx.x * 256;
  const int nt = K >> 6;            // must be even, >= 2

  const int sRow   = tid >> 3;                    // 0..63
  const int sChunk = (tid & 7) ^ (sRow & 7);
  const size_t ldaS = (size_t)lda, ldbS = (size_t)ldb;
  const u16* aS = Ab + (size_t)(rowBase + sRow) * ldaS + sChunk * 8;
  const u16* bS = Bb + (size_t)(colBase + sRow) * ldbS + sChunk * 8;

  const int fr = lane & 15;
  const int kx = lane >> 4;
  const int rx = lane & 7;

  f32x4 acc[4][4];
  const f32x4 zf = {0.f, 0.f, 0.f, 0.f};
#pragma unroll
  for (int m = 0; m < 4; ++m)
#pragma unroll
    for (int n = 0; n < 4; ++n) acc[m][n] = zf;

  bf16x8 Ara[4][2], Arb[4][2], Bra[2][2], Brb[2][2];

  // A tile = 128 rows = 16KB = 2 gload_lds/thread (rows sRow, sRow+64).
  auto stageA = [&](int buf, int kt) {
    const u16* s = aS + kt;
    char* d = ((char*)&As[buf][0]) + tid * 16;
    gload_lds16(s, d);
    gload_lds16(s + 64 * ldaS, d + 8192);
  };
  auto stageB = [&](int buf, int h, int kt) {
    const u16* s = bS + (size_t)(h * 128) * ldbS + kt;
    char* d = ((char*)&Bs[buf][0]) + h * 16384 + tid * 16;
    gload_lds16(s, d);
    gload_lds16(s + 64 * ldbS, d + 8192);
  };
  auto ldsA = [&](int buf, bf16x8 (&dst)[4][2]) {
#pragma unroll
    for (int j = 0; j < 4; ++j) {
      const int row = wr * 64 + j * 16 + fr;            // < 128
#pragma unroll
      for (int k = 0; k < 2; ++k) {
        const int ch = ((k * 4 + kx) ^ rx) * 8;
        dst[j][k] = *(const bf16x8*)&As[buf][row * 64 + ch];
      }
    }
  };
  auto ldsB = [&](int buf, int nq, bf16x8 (&dst)[2][2]) {
#pragma unroll
    for (int i = 0; i < 2; ++i) {
      const int row = nq * 128 + i * 64 + wc * 16 + fr;
#pragma unroll
      for (int k = 0; k < 2; ++k) {
        const int ch = ((k * 4 + kx) ^ rx) * 8;
        dst[i][k] = *(const bf16x8*)&Bs[buf][row * 64 + ch];
      }
    }
  };

  // one tile; ACUR holds A(t) at entry, ANXT receives A(t+1).
  auto tile = [&](int t, int c, bf16x8 (&ACUR)[4][2], bf16x8 (&ANXT)[4][2]) {
    const int kt1 = (t + 1) << 6;
    const bool s1 = (t + 1 < nt);
    ldsB(c, 1, Brb);            // Bq1(t), 4 reads; consumer MQS(0,1)
    if (s1) {
      stageA(1 - c, kt1);       // 2 vmem
      stageB(1 - c, 0, kt1);    // 4 vmem
      stageB(1 - c, 1, kt1);
    }
    MQS(0, 0, ACUR, Bra);       // acc cols 0,1; last use of Bra=Bq0(t)
    if (s1) {
      asm volatile("s_waitcnt lgkmcnt(0)" ::: "memory");
      asm volatile("s_waitcnt vmcnt(0)" ::: "memory");
      BARRIER();
      ldsA(1 - c, ANXT);        // A(t+1), 8 reads; drains under MQS(0,1)
      ldsB(1 - c, 0, Bra);      // Bq0(t+1), 4 reads
      __builtin_amdgcn_sched_barrier(0);
    }
    MQS(0, 1, ACUR, Brb);       // acc cols 2,3
  };

  // prologue: tile0 -> buf0 (A 2 + B 4 vmem), first reg sets.
  stageA(0, 0);
  stageB(0, 0, 0);
  stageB(0, 1, 0);
  asm volatile("s_waitcnt vmcnt(0)" ::: "memory");
  BARRIER();
  ldsA(0, Ara);                 // A(0)
  ldsB(0, 0, Bra);              // Bq0(0)

  for (int tt = 0; tt < nt; tt += 2) {
    tile(tt,     0, Ara, Arb);  // even tile reads buf0, stages buf1
    tile(tt + 1, 1, Arb, Ara);  // odd tile reads buf1, stages buf0
  }

  // epilogue: C/D layout col=lane&15, row=(lane>>4)*4+reg [m89-verified]
  const int r0 = (lane >> 4) * 4;
#pragma unroll
  for (int m = 0; m < 4; ++m) {
    const int grow = rowBase + wr * 64 + m * 16 + r0;
#pragma unroll
    for (int jj = 0; jj < 4; ++jj) {
      const size_t rOff = (size_t)(grow + jj) * (size_t)ldc;
      if constexpr (BF16OUT) {
        u16* C = (u16*)Cv + z * sCz;
#pragma unroll
        for (int n = 0; n < 4; ++n) {
          const int gcol = colBase + (n >> 1) * 128 + (n & 1) * 64 + wc * 16 + fr;
          C[rOff + gcol] = f2bf(acc[m][n][jj] * alpha);
        }
      } else {
        float* C = (float*)Cv + z * sCz;
#pragma unroll
        for (int n = 0; n < 4; ++n) {
          const int gcol = colBase + (n >> 1) * 128 + (n & 1) * 64 + wc * 16 + fr;
          C[rOff + gcol] = acc[m][n][jj] * alpha;
        }
      }
    }
  }
}

// ---------------------------------------------------------------------------
// v transpose: qkv[(t*4+b)*3072 + 2048 + e] -> vT[b][e][t]  (bf16)
// ---------------------------------------------------------------------------
__global__ __launch_bounds__(256)
void transpose_v(const u16* __restrict__ qkv, u16* __restrict__ vT) {
  __shared__ u16 tile[64][72];
  const int b  = blockIdx.z;
  const int t0 = blockIdx.x * 64;
  const int e0 = blockIdx.y * 64;
  const int tid = threadIdx.x;
  const int r  = tid >> 3;
  const int c8 = (tid & 7) * 8;
#pragma unroll
  for (int p = 0; p < 2; ++p) {
    const int t = t0 + p * 32 + r;
    const u16* src = qkv + (size_t)(t * 4 + b) * 3072 + 2048 + e0 + c8;
    *(u16x8*)&tile[p * 32 + r][c8] = *(const u16x8*)src;
  }
  __syncthreads();
#pragma unroll
  for (int p = 0; p < 2; ++p) {
    const int e = p * 32 + r;
    u16x8 v;
#pragma unroll
    for (int j = 0; j < 8; ++j) v[j] = tile[c8 + j][e];
    *(u16x8*)(vT + (size_t)b * 2097152 + (size_t)(e0 + e) * 2048 + t0 + c8) = v;
  }
}

// ---------------------------------------------------------------------------
// Row softmax over 2048 cols: reads bf16 scores (already scaled by 1/32),
// writes fp32 weights (required output) + bf16 probs IN PLACE over scores.
// ---------------------------------------------------------------------------
__global__ __launch_bounds__(256)
void softmax_rows(u16* __restrict__ sbf, float* __restrict__ wfp) {
  const size_t row = blockIdx.x;
  const int tid = threadIdx.x;
  u16* pb = sbf + row * 2048;
  u16x8 xb = *(const u16x8*)(pb + tid * 8);
  float x[8];
#pragma unroll
  for (int j = 0; j < 8; ++j) x[j] = bf2f(xb[j]);
  float m = x[0];
#pragma unroll
  for (int j = 1; j < 8; ++j) m = fmaxf(m, x[j]);
#pragma unroll
  for (int o = 32; o; o >>= 1) m = fmaxf(m, __shfl_xor(m, o, 64));
  __shared__ float red[8];
  if ((tid & 63) == 0) red[tid >> 6] = m;
  __syncthreads();
  m = fmaxf(fmaxf(red[0], red[1]), fmaxf(red[2], red[3]));
  float e[8];
  float s = 0.f;
#pragma unroll
  for (int j = 0; j < 8; ++j) { e[j] = expf(x[j] - m); s += e[j]; }
#pragma unroll
  for (int o = 32; o; o >>= 1) s += __shfl_xor(s, o, 64);
  if ((tid & 63) == 0) red[4 + (tid >> 6)] = s;
  __syncthreads();
  s = (red[4] + red[5]) + (red[6] + red[7]);
  const float inv = 1.0f / s;
  float w[8];
#pragma unroll
  for (int j = 0; j < 8; ++j) w[j] = e[j] * inv;
  float* pf = wfp + row * 2048;
  float4 o0 = {w[0], w[1], w[2], w[3]};
  float4 o1 = {w[4], w[5], w[6], w[7]};
  ((float4*)pf)[tid * 2] = o0;
  ((float4*)pf)[tid * 2 + 1] = o1;
  u16x8 ub;
#pragma unroll
  for (int j = 0; j < 8; ++j) ub[j] = f2bf(w[j]);
  *(u16x8*)(pb + tid * 8) = ub;
}

// ---------------------------------------------------------------------------
// S=2048, B=4, E=1024. inputs: Q, K(ignored), V(ignored), W_in, W_out (fp32)
// outputs: out [2048,4,1024] fp32 | weights [4,2048,2048] fp32
// ---------------------------------------------------------------------------
extern "C" void kernel_launch(void* const* d_in, const int* in_sizes, int n_in,
                              void* d_out, int out_size, void* d_ws, size_t ws_size,
                              hipStream_t stream) {
  const float* Q  = (const float*)d_in[0];
  const float* Wi = (const float*)d_in[3];
  const float* Wo = (const float*)d_in[4];
  float* out0    = (float*)d_out;
  float* weights = out0 + (size_t)2048 * 4 * 1024;  // 8388608

  char* ws = (char*)d_ws;
  u16* Qb   = (u16*)(ws);                          // 16 MiB [8192][1024]
  u16* Wib  = (u16*)(ws + ((size_t)16 << 20));     //  6 MiB [3072][1024]
  u16* Wob  = (u16*)(ws + ((size_t)22 << 20));     //  2 MiB [1024][1024]
  u16* qkvb = (u16*)(ws + ((size_t)24 << 20));     // 48 MiB [8192][3072]
  u16* vT   = (u16*)(ws + ((size_t)72 << 20));     // 16 MiB [4][1024][2048]
  u16* wbf  = (u16*)(ws + ((size_t)88 << 20));     // 32 MiB [4][2048][2048]
  u16* attb = Qb;  // alias: Qb dead after gemm1. [t][b][e] = [8192][1024]

  // 1) converts
  cvt_bf16<<<dim3(8192), dim3(256), 0, stream>>>(Q,  Qb,  2097152);
  cvt_bf16<<<dim3(3072), dim3(256), 0, stream>>>(Wi, Wib, 786432);
  cvt_bf16<<<dim3(1024), dim3(256), 0, stream>>>(Wo, Wob, 262144);

  // 2) qkv = Q * W_in^T : [8192,1024] x [3072,1024]^T -> bf16 [8192,3072]
  gemm256<true><<<dim3(12, 32, 1), dim3(512), 0, stream>>>(
      Qb, Wib, (void*)qkvb, 1024, 1024, 3072, 0, 0, 0, 1024, 1.0f);

  // 3) vT[b][e][t] from qkv v-part
  transpose_v<<<dim3(32, 16, 4), dim3(256), 0, stream>>>(qkvb, vT);

  // 4) scores[b] = (q/32) k^T -> bf16 directly into wbf (256 blocks, clean)
  gemm256<true><<<dim3(8, 8, 4), dim3(512), 0, stream>>>(
      qkvb, qkvb + 1024, (void*)wbf, 12288, 12288, 2048,
      3072LL, 3072LL, 4194304LL, 1024, 0.03125f);

  // 5) softmax: bf16 scores -> fp32 weights (d_out) + bf16 probs in place
  softmax_rows<<<dim3(8192), dim3(256), 0, stream>>>(wbf, weights);

  // 6) att[t][b][e] = probs[b] * v[b]  -- 128-row tiles: 4x16x4 = 256 blocks
  gemm128<true><<<dim3(4, 16, 4), dim3(512), 0, stream>>>(
      wbf, vT, (void*)attb, 2048, 2048, 4096,
      4194304LL, 2097152LL, 1024LL, 2048, 1.0f);

  // 7) out = att * W_out^T -- 128-row tiles: 4x64 = 256 blocks
  gemm128<false><<<dim3(4, 64, 1), dim3(512), 0, stream>>>(
      attb, Wob, (void*)out0, 1024, 1024, 1024, 0, 0, 0, 1024, 1.0f);
}

// Round 8
// 211.570 us; speedup vs baseline: 1.6257x; 1.0445x over previous
//
#include <hip/hip_runtime.h>
#include <stdint.h>

typedef unsigned short u16;
typedef __bf16 bf16_t;
typedef bf16_t bf16x8 __attribute__((ext_vector_type(8)));
typedef float f32x4 __attribute__((ext_vector_type(4)));
typedef u16 u16x4 __attribute__((ext_vector_type(4)));
typedef u16 u16x8 __attribute__((ext_vector_type(8)));

#define AS1 __attribute__((address_space(1)))
#define AS3 __attribute__((address_space(3)))

__device__ __forceinline__ u16 f2bf(float f) {
  union { float f; uint32_t u; } x; x.f = f;
  uint32_t u = x.u;
  return (u16)((u + 0x7fffu + ((u >> 16) & 1u)) >> 16);  // RNE
}

__device__ __forceinline__ float bf2f(u16 b) {
  union { uint32_t u; float f; } x; x.u = ((uint32_t)b) << 16;
  return x.f;
}

__device__ __forceinline__ void gload_lds16(const void* g, void* lds) {
  __builtin_amdgcn_global_load_lds((const AS1 uint32_t*)g, (AS3 uint32_t*)lds, 16, 0, 0);
}

// ---------------------------------------------------------------------------
// fp32 -> bf16 elementwise convert
// ---------------------------------------------------------------------------
__global__ __launch_bounds__(256) void cvt_bf16(const float* __restrict__ in,
                                                u16* __restrict__ out, int n4) {
  int i = blockIdx.x * 256 + threadIdx.x;
  if (i >= n4) return;
  float4 v = ((const float4*)in)[i];
  u16x4 o = {f2bf(v.x), f2bf(v.y), f2bf(v.z), f2bf(v.w)};
  *(u16x4*)(out + (size_t)i * 4) = o;
}

// ---------------------------------------------------------------------------
// Session record (r0-r7): per 256x256x64 tile ~4875cyc = LDS-port (~2800) +
// MFMA (~2370) + sync, SUM behavior, invariant across 5 schedule variants.
// gemm128 tile ~4225cyc (half FLOPs, same fixed sync) -- worse per-FLOP but
// packs 2x more blocks. At 1 block/CU (register-pinned), grid packing vs
// 256 CUs is first-order: this round restructures the WORK GRAPH with the
// two proven kernels unchanged: (a) qkv split 256+128-col parts so both
// dispatches are exactly 256 blocks; (b) associativity out = P*(V*Wo^T):
// VWT = Wo*V^T then out' = P*VWT^T -- same FLOPs, transpose_v deleted.
// ---------------------------------------------------------------------------
#define BARRIER() do { asm volatile("" ::: "memory"); \
                       __builtin_amdgcn_s_barrier();  \
                       asm volatile("" ::: "memory"); } while (0)

#define MQS(MQi, NQi, ASET, BSET)                                              \
  do {                                                                         \
    __builtin_amdgcn_s_setprio(1);                                             \
    _Pragma("unroll") for (int j_ = 0; j_ < 4; ++j_) {                         \
      _Pragma("unroll") for (int i_ = 0; i_ < 2; ++i_) {                       \
        acc[(MQi) * 4 + j_][(NQi) * 2 + i_] =                                  \
            __builtin_amdgcn_mfma_f32_16x16x32_bf16(                           \
                ASET[j_][0], BSET[i_][0],                                      \
                acc[(MQi) * 4 + j_][(NQi) * 2 + i_], 0, 0, 0);                 \
        acc[(MQi) * 4 + j_][(NQi) * 2 + i_] =                                  \
            __builtin_amdgcn_mfma_f32_16x16x32_bf16(                           \
                ASET[j_][1], BSET[i_][1],                                      \
                acc[(MQi) * 4 + j_][(NQi) * 2 + i_], 0, 0, 0);                 \
      }                                                                        \
    }                                                                          \
    __builtin_amdgcn_s_setprio(0);                                             \
  } while (0)

// ---------------------------------------------------------------------------
// gemm256: 256x256 tile, 8 waves 2Mx4N, reg-dbuf (round-3 winner, FROZEN).
// A: [M][K] lda, B: [N][K] ldb, C: [M][N] ldc, z via sAz/sBz/sCz.
// M=gridDim.y*256, N=gridDim.x*256, K%64==0, nt>=2.
// ---------------------------------------------------------------------------
template <bool BF16OUT>
__global__ __launch_bounds__(512, 2)
void gemm256(const u16* __restrict__ A, const u16* __restrict__ B,
             void* __restrict__ Cv,
             int lda, int ldb, int ldc,
             long long sAz, long long sBz, long long sCz,
             int K, float alpha) {
  __shared__ u16 As[2][256 * 64];   // 64 KiB
  __shared__ u16 Bs[2][256 * 64];   // 64 KiB
  const int tid  = threadIdx.x;
  const int lane = tid & 63;
  const int wid  = tid >> 6;        // 0..7
  const int wr   = wid >> 2;        // 0..1
  const int wc   = wid & 3;         // 0..3
  const long long z = blockIdx.z;
  const u16* Ab = A + z * sAz;
  const u16* Bb = B + z * sBz;
  const int rowBase = blockIdx.y * 256;
  const int colBase = blockIdx.x * 256;
  const int nt = K >> 6;

  const int sRow   = tid >> 3;                    // 0..63
  const int sChunk = (tid & 7) ^ (sRow & 7);      // rule-21 involution
  const size_t ldaS = (size_t)lda, ldbS = (size_t)ldb;
  const u16* aS = Ab + (size_t)(rowBase + sRow) * ldaS + sChunk * 8;
  const u16* bS = Bb + (size_t)(colBase + sRow) * ldbS + sChunk * 8;

  const int fr = lane & 15;
  const int kx = lane >> 4;
  const int rx = lane & 7;

  f32x4 acc[8][4];
  const f32x4 zf = {0.f, 0.f, 0.f, 0.f};
#pragma unroll
  for (int m = 0; m < 8; ++m)
#pragma unroll
    for (int n = 0; n < 4; ++n) acc[m][n] = zf;

  bf16x8 Ara[4][2], Arb[4][2], Bra[2][2], Brb[2][2];

  auto stageA = [&](int buf, int h, int kt) {
    const u16* s = aS + (size_t)(h * 128) * ldaS + kt;
    char* d = ((char*)&As[buf][0]) + h * 16384 + tid * 16;
    gload_lds16(s, d);
    gload_lds16(s + 64 * ldaS, d + 8192);
  };
  auto stageB = [&](int buf, int h, int kt) {
    const u16* s = bS + (size_t)(h * 128) * ldbS + kt;
    char* d = ((char*)&Bs[buf][0]) + h * 16384 + tid * 16;
    gload_lds16(s, d);
    gload_lds16(s + 64 * ldbS, d + 8192);
  };
  auto ldsA = [&](int buf, int mq, bf16x8 (&dst)[4][2]) {
#pragma unroll
    for (int j = 0; j < 4; ++j) {
      const int row = mq * 128 + wr * 64 + j * 16 + fr;
#pragma unroll
      for (int k = 0; k < 2; ++k) {
        const int ch = ((k * 4 + kx) ^ rx) * 8;
        dst[j][k] = *(const bf16x8*)&As[buf][row * 64 + ch];
      }
    }
  };
  auto ldsB = [&](int buf, int nq, bf16x8 (&dst)[2][2]) {
#pragma unroll
    for (int i = 0; i < 2; ++i) {
      const int row = nq * 128 + i * 64 + wc * 16 + fr;
#pragma unroll
      for (int k = 0; k < 2; ++k) {
        const int ch = ((k * 4 + kx) ^ rx) * 8;
        dst[i][k] = *(const bf16x8*)&Bs[buf][row * 64 + ch];
      }
    }
  };

  stageA(0, 0, 0);
  stageA(0, 1, 0);
  stageB(0, 0, 0);
  stageB(0, 1, 0);
  asm volatile("s_waitcnt vmcnt(0)" ::: "memory");
  BARRIER();
  ldsA(0, 0, Ara);              // A0(0)
  ldsB(0, 0, Bra);              // B0(0)

  for (int t = 0; t < nt; ++t) {
    const int c = t & 1;
    const int kt1 = (t + 1) << 6;
    const bool s1 = (t + 1 < nt);
    ldsB(c, 1, Brb);            // B1(t)
    ldsA(c, 1, Arb);            // A1(t)
    if (s1) {
      stageA(1 - c, 0, kt1);
      stageA(1 - c, 1, kt1);
      stageB(1 - c, 0, kt1);
      stageB(1 - c, 1, kt1);
    }
    MQS(0, 0, Ara, Bra);
    MQS(0, 1, Ara, Brb);
    if (s1) {
      asm volatile("s_waitcnt lgkmcnt(0)" ::: "memory");
      asm volatile("s_waitcnt vmcnt(0)" ::: "memory");
      BARRIER();
      ldsA(1 - c, 0, Ara);      // A0(t+1)
      __builtin_amdgcn_sched_barrier(0);
    }
    MQS(1, 0, Arb, Bra);
    if (s1) ldsB(1 - c, 0, Bra);// B0(t+1)
    MQS(1, 1, Arb, Brb);
  }

  const int r0 = (lane >> 4) * 4;
#pragma unroll
  for (int m = 0; m < 8; ++m) {
    const int grow = rowBase + (m >> 2) * 128 + wr * 64 + (m & 3) * 16 + r0;
#pragma unroll
    for (int jj = 0; jj < 4; ++jj) {
      const size_t rOff = (size_t)(grow + jj) * (size_t)ldc;
      if constexpr (BF16OUT) {
        u16* C = (u16*)Cv + z * sCz;
#pragma unroll
        for (int n = 0; n < 4; ++n) {
          const int gcol = colBase + (n >> 1) * 128 + (n & 1) * 64 + wc * 16 + fr;
          C[rOff + gcol] = f2bf(acc[m][n][jj] * alpha);
        }
      } else {
        float* C = (float*)Cv + z * sCz;
#pragma unroll
        for (int n = 0; n < 4; ++n) {
          const int gcol = colBase + (n >> 1) * 128 + (n & 1) * 64 + wc * 16 + fr;
          C[rOff + gcol] = acc[m][n][jj] * alpha;
        }
      }
    }
  }
}

// ---------------------------------------------------------------------------
// gemm128: 128x256 tile (packing variant; round-7 verified). 8 waves 2Mx4N,
// wave owns 64x64, acc[4][4]. A reg sets alternate per tile via unroll-of-2;
// LDS 96KiB. nt = K/64 EVEN, >= 2. M=gridDim.y*128, N=gridDim.x*256.
// ---------------------------------------------------------------------------
template <bool BF16OUT>
__global__ __launch_bounds__(512, 2)
void gemm128(const u16* __restrict__ A, const u16* __restrict__ B,
             void* __restrict__ Cv,
             int lda, int ldb, int ldc,
             long long sAz, long long sBz, long long sCz,
             int K, float alpha) {
  __shared__ u16 As[2][128 * 64];   // 32 KiB
  __shared__ u16 Bs[2][256 * 64];   // 64 KiB
  const int tid  = threadIdx.x;
  const int lane = tid & 63;
  const int wid  = tid >> 6;        // 0..7
  const int wr   = wid >> 2;        // 0..1
  const int wc   = wid & 3;         // 0..3
  const long long z = blockIdx.z;
  const u16* Ab = A + z * sAz;
  const u16* Bb = B + z * sBz;
  const int rowBase = blockIdx.y * 128;
  const int colBase = blockIdx.x * 256;
  const int nt = K >> 6;            // must be even, >= 2

  const int sRow   = tid >> 3;                    // 0..63
  const int sChunk = (tid & 7) ^ (sRow & 7);
  const size_t ldaS = (size_t)lda, ldbS = (size_t)ldb;
  const u16* aS = Ab + (size_t)(rowBase + sRow) * ldaS + sChunk * 8;
  const u16* bS = Bb + (size_t)(colBase + sRow) * ldbS + sChunk * 8;

  const int fr = lane & 15;
  const int kx = lane >> 4;
  const int rx = lane & 7;

  f32x4 acc[4][4];
  const f32x4 zf = {0.f, 0.f, 0.f, 0.f};
#pragma unroll
  for (int m = 0; m < 4; ++m)
#pragma unroll
    for (int n = 0; n < 4; ++n) acc[m][n] = zf;

  bf16x8 Ara[4][2], Arb[4][2], Bra[2][2], Brb[2][2];

  auto stageA = [&](int buf, int kt) {
    const u16* s = aS + kt;
    char* d = ((char*)&As[buf][0]) + tid * 16;
    gload_lds16(s, d);
    gload_lds16(s + 64 * ldaS, d + 8192);
  };
  auto stageB = [&](int buf, int h, int kt) {
    const u16* s = bS + (size_t)(h * 128) * ldbS + kt;
    char* d = ((char*)&Bs[buf][0]) + h * 16384 + tid * 16;
    gload_lds16(s, d);
    gload_lds16(s + 64 * ldbS, d + 8192);
  };
  auto ldsA = [&](int buf, bf16x8 (&dst)[4][2]) {
#pragma unroll
    for (int j = 0; j < 4; ++j) {
      const int row = wr * 64 + j * 16 + fr;            // < 128
#pragma unroll
      for (int k = 0; k < 2; ++k) {
        const int ch = ((k * 4 + kx) ^ rx) * 8;
        dst[j][k] = *(const bf16x8*)&As[buf][row * 64 + ch];
      }
    }
  };
  auto ldsB = [&](int buf, int nq, bf16x8 (&dst)[2][2]) {
#pragma unroll
    for (int i = 0; i < 2; ++i) {
      const int row = nq * 128 + i * 64 + wc * 16 + fr;
#pragma unroll
      for (int k = 0; k < 2; ++k) {
        const int ch = ((k * 4 + kx) ^ rx) * 8;
        dst[i][k] = *(const bf16x8*)&Bs[buf][row * 64 + ch];
      }
    }
  };

  auto tile = [&](int t, int c, bf16x8 (&ACUR)[4][2], bf16x8 (&ANXT)[4][2]) {
    const int kt1 = (t + 1) << 6;
    const bool s1 = (t + 1 < nt);
    ldsB(c, 1, Brb);            // Bq1(t)
    if (s1) {
      stageA(1 - c, kt1);
      stageB(1 - c, 0, kt1);
      stageB(1 - c, 1, kt1);
    }
    MQS(0, 0, ACUR, Bra);       // acc cols 0,1; last use of Bra=Bq0(t)
    if (s1) {
      asm volatile("s_waitcnt lgkmcnt(0)" ::: "memory");
      asm volatile("s_waitcnt vmcnt(0)" ::: "memory");
      BARRIER();
      ldsA(1 - c, ANXT);        // A(t+1)
      ldsB(1 - c, 0, Bra);      // Bq0(t+1)
      __builtin_amdgcn_sched_barrier(0);
    }
    MQS(0, 1, ACUR, Brb);       // acc cols 2,3
  };

  stageA(0, 0);
  stageB(0, 0, 0);
  stageB(0, 1, 0);
  asm volatile("s_waitcnt vmcnt(0)" ::: "memory");
  BARRIER();
  ldsA(0, Ara);                 // A(0)
  ldsB(0, 0, Bra);              // Bq0(0)

  for (int tt = 0; tt < nt; tt += 2) {
    tile(tt,     0, Ara, Arb);
    tile(tt + 1, 1, Arb, Ara);
  }

  const int r0 = (lane >> 4) * 4;
#pragma unroll
  for (int m = 0; m < 4; ++m) {
    const int grow = rowBase + wr * 64 + m * 16 + r0;
#pragma unroll
    for (int jj = 0; jj < 4; ++jj) {
      const size_t rOff = (size_t)(grow + jj) * (size_t)ldc;
      if constexpr (BF16OUT) {
        u16* C = (u16*)Cv + z * sCz;
#pragma unroll
        for (int n = 0; n < 4; ++n) {
          const int gcol = colBase + (n >> 1) * 128 + (n & 1) * 64 + wc * 16 + fr;
          C[rOff + gcol] = f2bf(acc[m][n][jj] * alpha);
        }
      } else {
        float* C = (float*)Cv + z * sCz;
#pragma unroll
        for (int n = 0; n < 4; ++n) {
          const int gcol = colBase + (n >> 1) * 128 + (n & 1) * 64 + wc * 16 + fr;
          C[rOff + gcol] = acc[m][n][jj] * alpha;
        }
      }
    }
  }
}

// ---------------------------------------------------------------------------
// Row softmax over 2048 cols: reads bf16 scores (already scaled by 1/32),
// writes fp32 weights (required output) + bf16 probs IN PLACE over scores.
// ---------------------------------------------------------------------------
__global__ __launch_bounds__(256)
void softmax_rows(u16* __restrict__ sbf, float* __restrict__ wfp) {
  const size_t row = blockIdx.x;
  const int tid = threadIdx.x;
  u16* pb = sbf + row * 2048;
  u16x8 xb = *(const u16x8*)(pb + tid * 8);
  float x[8];
#pragma unroll
  for (int j = 0; j < 8; ++j) x[j] = bf2f(xb[j]);
  float m = x[0];
#pragma unroll
  for (int j = 1; j < 8; ++j) m = fmaxf(m, x[j]);
#pragma unroll
  for (int o = 32; o; o >>= 1) m = fmaxf(m, __shfl_xor(m, o, 64));
  __shared__ float red[8];
  if ((tid & 63) == 0) red[tid >> 6] = m;
  __syncthreads();
  m = fmaxf(fmaxf(red[0], red[1]), fmaxf(red[2], red[3]));
  float e[8];
  float s = 0.f;
#pragma unroll
  for (int j = 0; j < 8; ++j) { e[j] = expf(x[j] - m); s += e[j]; }
#pragma unroll
  for (int o = 32; o; o >>= 1) s += __shfl_xor(s, o, 64);
  if ((tid & 63) == 0) red[4 + (tid >> 6)] = s;
  __syncthreads();
  s = (red[4] + red[5]) + (red[6] + red[7]);
  const float inv = 1.0f / s;
  float w[8];
#pragma unroll
  for (int j = 0; j < 8; ++j) w[j] = e[j] * inv;
  float* pf = wfp + row * 2048;
  float4 o0 = {w[0], w[1], w[2], w[3]};
  float4 o1 = {w[4], w[5], w[6], w[7]};
  ((float4*)pf)[tid * 2] = o0;
  ((float4*)pf)[tid * 2 + 1] = o1;
  u16x8 ub;
#pragma unroll
  for (int j = 0; j < 8; ++j) ub[j] = f2bf(w[j]);
  *(u16x8*)(pb + tid * 8) = ub;
}

// ---------------------------------------------------------------------------
// S=2048, B=4, E=1024. inputs: Q, K(ignored), V(ignored), W_in, W_out (fp32)
// outputs: out [2048,4,1024] fp32 | weights [4,2048,2048] fp32
// Graph: cvt -> qkv(p1 q,k | p2 v) -> {scores -> softmax | VWT} -> out'
// with out = P * (V * Wo^T)   [associativity; same FLOPs, no transpose_v]
// ---------------------------------------------------------------------------
extern "C" void kernel_launch(void* const* d_in, const int* in_sizes, int n_in,
                              void* d_out, int out_size, void* d_ws, size_t ws_size,
                              hipStream_t stream) {
  const float* Q  = (const float*)d_in[0];
  const float* Wi = (const float*)d_in[3];
  const float* Wo = (const float*)d_in[4];
  float* out0    = (float*)d_out;
  float* weights = out0 + (size_t)2048 * 4 * 1024;  // 8388608

  char* ws = (char*)d_ws;
  u16* Qb   = (u16*)(ws);                          // 16 MiB [8192][1024]
  u16* Wib  = (u16*)(ws + ((size_t)16 << 20));     //  6 MiB [3072][1024]
  u16* Wob  = (u16*)(ws + ((size_t)22 << 20));     //  2 MiB [1024][1024]
  u16* qkvb = (u16*)(ws + ((size_t)24 << 20));     // 48 MiB [8192][3072]
  u16* vwT  = (u16*)(ws + ((size_t)72 << 20));     // 16 MiB [4][1024f][2048s]
  u16* wbf  = (u16*)(ws + ((size_t)88 << 20));     // 32 MiB [4][2048][2048]

  // 1) converts
  cvt_bf16<<<dim3(8192), dim3(256), 0, stream>>>(Q,  Qb,  2097152);
  cvt_bf16<<<dim3(3072), dim3(256), 0, stream>>>(Wi, Wib, 786432);
  cvt_bf16<<<dim3(1024), dim3(256), 0, stream>>>(Wo, Wob, 262144);

  // 2a) qkv cols 0..2047 (q,k): 8x32 = 256 blocks, exactly 1 round
  gemm256<true><<<dim3(8, 32, 1), dim3(512), 0, stream>>>(
      Qb, Wib, (void*)qkvb, 1024, 1024, 3072, 0, 0, 0, 1024, 1.0f);

  // 2b) qkv cols 2048..3071 (v): 128-row tiles, 4x64 = 256 blocks
  gemm128<true><<<dim3(4, 64, 1), dim3(512), 0, stream>>>(
      Qb, Wib + (size_t)2048 * 1024, (void*)(qkvb + 2048),
      1024, 1024, 3072, 0, 0, 0, 1024, 1.0f);

  // 3) scores[b] = (q/32) k^T -> bf16 into wbf (8x8x4 = 256 blocks)
  gemm256<true><<<dim3(8, 8, 4), dim3(512), 0, stream>>>(
      qkvb, qkvb + 1024, (void*)wbf, 12288, 12288, 2048,
      3072LL, 3072LL, 4194304LL, 1024, 0.03125f);

  // 4) VWT[b][f][s] = sum_e Wo[f,e] v[b,s,e]  (A=Wob shared, B=v rows)
  //    8x8x4 = 256 blocks, nt=16
  gemm128<true><<<dim3(8, 8, 4), dim3(512), 0, stream>>>(
      Wob, qkvb + 2048, (void*)vwT, 1024, 12288, 2048,
      0LL, 3072LL, 2097152LL, 1024, 1.0f);

  // 5) softmax: bf16 scores -> fp32 weights (d_out) + bf16 probs in place
  softmax_rows<<<dim3(8192), dim3(256), 0, stream>>>(wbf, weights);

  // 6) out[t,b,f] = sum_s P[b,t,s] VWT[b,f,s] -> fp32 d_out directly
  //    4x16x4 = 256 blocks, nt=32
  gemm128<false><<<dim3(4, 16, 4), dim3(512), 0, stream>>>(
      wbf, vwT, (void*)out0, 2048, 2048, 4096,
      4194304LL, 2097152LL, 1024LL, 2048, 1.0f);
}